// Round 1
// baseline (57.460 us; speedup 1.0000x reference)
//
#include <hip/hip_runtime.h>

#define ALPHA 0.05f

__global__ __launch_bounds__(256) void dataterm_kernel(
    const float* __restrict__ I1,
    const float* __restrict__ I2,
    const float* __restrict__ flow,
    float* __restrict__ out,
    int H, int W, int total)
{
    int idx = blockIdx.x * blockDim.x + threadIdx.x;
    if (idx >= total) return;

    int x = idx % W;
    int t = idx / W;
    int y = t % H;
    int b = t / H;

    int base = b * H * W;
    int pix = base + y * W + x;

    float i1 = I1[pix];
    // NOTE: reference swaps names — "grad_x" is the dy (vertical) difference,
    // "grad_y" is the dx (horizontal) difference. Last row / col are zero.
    float g_dy = (y < H - 1) ? (I1[pix + W] - i1) : 0.0f;
    float g_dx = (x < W - 1) ? (I1[pix + 1] - i1) : 0.0f;

    float2 uv = reinterpret_cast<const float2*>(flow)[idx];
    float u = uv.x, v = uv.y;

    // bilinear backward warp of I2 at (x+u, y+v), clamped to borders
    float xx = fminf(fmaxf((float)x + u, 0.0f), (float)(W - 1));
    float yy = fminf(fmaxf((float)y + v, 0.0f), (float)(H - 1));
    float x0f = floorf(xx);
    float y0f = floorf(yy);
    int x0 = (int)x0f;
    int y0 = (int)y0f;
    int x1 = min(x0 + 1, W - 1);
    int y1 = min(y0 + 1, H - 1);
    float wx = xx - x0f;
    float wy = yy - y0f;

    const float* I2b = I2 + base;
    float Ia = I2b[y0 * W + x0];
    float Ib = I2b[y0 * W + x1];
    float Ic = I2b[y1 * W + x0];
    float Id = I2b[y1 * W + x1];
    float top = Ia + wx * (Ib - Ia);
    float bot = Ic + wx * (Id - Ic);
    float warped = top + wy * (bot - top);

    float dataTerm = warped - i1;
    float un = u - ALPHA * dataTerm * g_dy;  // uses "grad_x" == dy per reference
    float vn = v - ALPHA * dataTerm * g_dx;  // uses "grad_y" == dx per reference

    reinterpret_cast<float2*>(out)[idx] = make_float2(un, vn);
}

extern "C" void kernel_launch(void* const* d_in, const int* in_sizes, int n_in,
                              void* d_out, int out_size, void* d_ws, size_t ws_size,
                              hipStream_t stream) {
    const float* I1   = (const float*)d_in[0];
    const float* I2   = (const float*)d_in[1];
    const float* flow = (const float*)d_in[2];
    float* out = (float*)d_out;

    const int B = 32, H = 512, W = 512;
    const int total = B * H * W;  // 8,388,608 pixels

    int block = 256;
    int grid = (total + block - 1) / block;
    dataterm_kernel<<<grid, block, 0, stream>>>(I1, I2, flow, out, H, W, total);
}